// Round 3
// 3633.675 us; speedup vs baseline: 1.4215x; 1.4215x over previous
//
#include <hip/hip_runtime.h>
#include <hip/hip_cooperative_groups.h>
#include <math.h>

namespace cg = cooperative_groups;

#define BB 64
#define TT 512
#define FF 512
#define HH 1024
#define NG 4096  // 4H

typedef _Float16 half8 __attribute__((ext_vector_type(8)));
typedef float f32x4 __attribute__((ext_vector_type(4)));
typedef unsigned long long u64;

__device__ __forceinline__ float sigm(float x) { return 1.0f / (1.0f + __expf(-x)); }
__device__ __forceinline__ float tanh_fast(float x) {
    x = fminf(fmaxf(x, -30.0f), 30.0f);
    float e = __expf(2.0f * x);
    return (e - 1.0f) / (e + 1.0f);
}

// ---------------------------------------------------------------------------
// x fp32 -> f16, same [B,T,F] layout. 32 MiB output into ws.
// ---------------------------------------------------------------------------
__global__ __launch_bounds__(256) void cvt_x(const float* __restrict__ x,
                                             _Float16* __restrict__ x16)
{
    size_t i = ((size_t)blockIdx.x * 256 + threadIdx.x) * 8;
    float4 a = *(const float4*)(x + i);
    float4 b = *(const float4*)(x + i + 4);
    half8 v;
    v[0] = (_Float16)a.x; v[1] = (_Float16)a.y; v[2] = (_Float16)a.z; v[3] = (_Float16)a.w;
    v[4] = (_Float16)b.x; v[5] = (_Float16)b.y; v[6] = (_Float16)b.z; v[7] = (_Float16)b.w;
    *(half8*)(x16 + i) = v;
}

// ---------------------------------------------------------------------------
// Persistent recurrence, batch-partitioned: 8 independent groups x 8 batches.
// Group = blockIdx.x>>5 (placement-agnostic: ALL cross-wg traffic is
// agent-scope at the memory-side LLC -- the round-0-proven protocol -- so
// correctness never depends on XCD assignment). 32 wgs/group cover all 4096
// gate-columns (128/wg: 8 waves x 16 cols). W_HH (128 VGPR) and W_XH
// (64 VGPR) are register-resident; LDS holds only the 16 KiB h tile + gbuf.
// Per-step sync: group-scope flag barrier (32 flags, direct poll, no epoch
// hop, NO per-step fence -- h is written with agent write-through stores and
// read with agent atomic loads, so caches never hold stale h, and read-only
// x16/weights/BN stay cache-resident across steps).
// MODE 0: x16 in ws.  MODE 1: fp32 x.  MODE 2: tiny-ws, grid.sync per step.
// h double-buffer: group-private 32 KiB chunk of d_out (2 x [8][1024] f16) =
// exactly that group's final fp32 output region (overwritten only after the
// group's last barrier).
// ---------------------------------------------------------------------------
template<int MODE>
__global__ __launch_bounds__(512, 2) void lstm_rec(
    const float* __restrict__ x, const float* __restrict__ w_xh,
    const float* __restrict__ w_hh, const float* __restrict__ bias,
    const float* __restrict__ scale, const float* __restrict__ offs,
    const float* __restrict__ pmean, const float* __restrict__ pvar,
    const _Float16* __restrict__ x16, int* flags,
    float* __restrict__ out)
{
    constexpr int HPAD = HH + 8;    // 1032 halves/row: +16 B/row bank skew

    __shared__ __align__(16) _Float16 h_lds[8 * HPAD];    // 16.1 KiB
    __shared__ float gbuf[8][8][17];                      // 4.25 KiB
    __shared__ float bias_l[128];

    const int tid  = threadIdx.x;
    const int lane = tid & 63, wid = tid >> 6;
    const int r = lane & 15, q = lane >> 4;
    const int arow = r & 7;             // A rows 8..15 duplicate 0..7 (M=8 real)

    const int g    = (int)blockIdx.x >> 5;   // batch group
    const int rank = (int)blockIdx.x & 31;   // rank within group
    int* gflags = flags + g * 64;            // 256 B per group, line-disjoint

    cg::grid_group grid = cg::this_grid();   // used only in MODE 2

    if (tid < 128) {
        int w = tid >> 4, nn = tid & 15;
        bias_l[tid] = bias[(nn >> 2) * HH + rank * 32 + w * 4 + (nn & 3)];
    }

    // group-private h double-buffer inside d_out
    _Float16* hbuf = (_Float16*)out + (size_t)g * (2 * 8 * HH);
    const int m = tid >> 5, j = tid & 31;    // epilogue: batch m, col j (tid<256)
    const int colg = rank * 32 + j;

    // zero h buffer 0 (this wg's 8x32 slice) -- agent write-through, at LLC
    if (tid < 256 && (j & 1) == 0)
        __hip_atomic_store((unsigned*)(hbuf + m * HH + colg), 0u,
                           __ATOMIC_RELAXED, __HIP_MEMORY_SCOPE_AGENT);

    // arrive ep=1 now; the long weight load below hides the barrier window.
    int ep = 1;
    __syncthreads();                    // compiler drains vmcnt before s_barrier
    if constexpr (MODE != 2) {
        if (tid == 0)
            __hip_atomic_store(&gflags[rank], ep, __ATOMIC_RELAXED,
                               __HIP_MEMORY_SCOPE_AGENT);
    }

    // ---- one-time weight residency (VGPRs) ----
    // this wave's 16 gate-cols: gate = r>>2, H-col = rank*32 + wid*4 + (r&3)
    const int mygcol = (r >> 2) * HH + rank * 32 + wid * 4 + (r & 3);
    half8 whh[32];                      // W_HH: 16 cols x K=1024 (128 VGPR)
    {
        const float* wp = w_hh + mygcol;
        #pragma unroll
        for (int kk = 0; kk < 32; ++kk) {
            const float* wk = wp + (size_t)(kk * 32 + q * 8) * NG;
            half8 f;
            #pragma unroll
            for (int jj = 0; jj < 8; ++jj) f[jj] = (_Float16)wk[(size_t)jj * NG];
            whh[kk] = f;
        }
    }
    half8 wxh[16];                      // W_XH: 16 cols x K=512 (64 VGPR)
    {
        const float* wp = w_xh + mygcol;
        #pragma unroll
        for (int kk = 0; kk < 16; ++kk) {
            const float* wk = wp + (size_t)(kk * 32 + q * 8) * NG;
            half8 f;
            #pragma unroll
            for (int jj = 0; jj < 8; ++jj) f[jj] = (_Float16)wk[(size_t)jj * NG];
            wxh[kk] = f;
        }
    }

    // step-0 BN params
    float bnmu = 0.f, bniss = 0.f, bnoff = 0.f;
    if (tid < 256) {
        bnmu  = pmean[colg];
        bniss = scale[colg] * rsqrtf(pvar[colg] + 1e-5f);
        bnoff = offs[colg];
    }

    // x-projection for step t (independent of h); B from VGPR-resident W_XH
    auto xgemm = [&](int t) -> f32x4 {
        f32x4 a4 = {0.f, 0.f, 0.f, 0.f};
        const int bm = g * 8 + arow;
        if constexpr (MODE == 0) {
            const _Float16* xr = x16 + ((size_t)bm * TT + t) * FF;
            #pragma unroll
            for (int kk = 0; kk < 16; ++kk) {
                half8 a = *(const half8*)(xr + kk * 32 + q * 8);
                a4 = __builtin_amdgcn_mfma_f32_16x16x32_f16(a, wxh[kk], a4, 0, 0, 0);
            }
        } else {
            const float* xr = x + ((size_t)bm * TT + t) * FF;
            #pragma unroll
            for (int kk = 0; kk < 16; ++kk) {
                int kb = kk * 32 + q * 8;
                float4 x0 = *(const float4*)(xr + kb);
                float4 x1 = *(const float4*)(xr + kb + 4);
                half8 a;
                a[0] = (_Float16)x0.x; a[1] = (_Float16)x0.y;
                a[2] = (_Float16)x0.z; a[3] = (_Float16)x0.w;
                a[4] = (_Float16)x1.x; a[5] = (_Float16)x1.y;
                a[6] = (_Float16)x1.z; a[7] = (_Float16)x1.w;
                a4 = __builtin_amdgcn_mfma_f32_16x16x32_f16(a, wxh[kk], a4, 0, 0, 0);
            }
        }
        return a4;
    };

    f32x4 xacc = xgemm(0);

    // wait ep=1: all group-mates have zeroed their h slices
    if constexpr (MODE == 2) {
        grid.sync();
    } else {
        if (tid < 64) {
            const int* fp = &gflags[tid & 31];
            for (;;) {
                int v = __hip_atomic_load(fp, __ATOMIC_RELAXED,
                                          __HIP_MEMORY_SCOPE_AGENT);
                if (__all(v >= ep)) break;
                __builtin_amdgcn_s_sleep(1);
            }
        }
        __syncthreads();
    }
    ++ep;

    // h staging: thread t handles 32 contiguous bytes (16 halves); one round
    // covers the group's full 8x1024 f16 tile (512 thr x 32 B = 16 KiB).
    const int e0 = tid * 16;
    const int srow = e0 >> 10, scol = e0 & 1023;

    float c_reg = 0.f, h_out = 0.f;
    int cur = 0;

    for (int t = 0; t < TT; ++t) {
        // ---- stage h_{t-1} into LDS (agent atomic loads: LLC-coherent) ----
        {
            const u64* hb = (const u64*)(hbuf + cur * (8 * HH) + e0);
            u64 v0 = __hip_atomic_load(hb + 0, __ATOMIC_RELAXED, __HIP_MEMORY_SCOPE_AGENT);
            u64 v1 = __hip_atomic_load(hb + 1, __ATOMIC_RELAXED, __HIP_MEMORY_SCOPE_AGENT);
            u64 v2 = __hip_atomic_load(hb + 2, __ATOMIC_RELAXED, __HIP_MEMORY_SCOPE_AGENT);
            u64 v3 = __hip_atomic_load(hb + 3, __ATOMIC_RELAXED, __HIP_MEMORY_SCOPE_AGENT);
            u64* dst = (u64*)&h_lds[srow * HPAD + scol];
            dst[0] = v0; dst[1] = v1; dst[2] = v2; dst[3] = v3;
        }
        __syncthreads();

        // ---- h-GEMM: K=1024, A from LDS, B from VGPR-resident W_HH ----
        f32x4 acc = xacc;
        #pragma unroll
        for (int kk = 0; kk < 32; ++kk) {
            half8 a = *(const half8*)&h_lds[arow * HPAD + kk * 32 + q * 8];
            acc = __builtin_amdgcn_mfma_f32_16x16x32_f16(a, whh[kk], acc, 0, 0, 0);
        }

        // ---- stage gates (C rows 0..7 live in q<2 lanes; col=r) ----
        if (q < 2) {
            #pragma unroll
            for (int reg = 0; reg < 4; ++reg)
                gbuf[wid][q * 4 + reg][r] = acc[reg];
        }
        __syncthreads();

        // ---- cell update: thread (m, j); wave j>>2 holds gates {d,4+d,8+d,12+d}
        if (tid < 256) {
            const int w4 = j >> 2, d = j & 3;
            float f_ = gbuf[w4][m][0  + d] + bias_l[w4 * 16 + 0  + d];
            float i_ = gbuf[w4][m][4  + d] + bias_l[w4 * 16 + 4  + d];
            float o_ = gbuf[w4][m][8  + d] + bias_l[w4 * 16 + 8  + d];
            float g_ = gbuf[w4][m][12 + d] + bias_l[w4 * 16 + 12 + d];
            c_reg = sigm(f_ + 1.0f) * c_reg + sigm(i_) * tanh_fast(g_);
            float cn = (c_reg - bnmu) * bniss + bnoff;
            h_out = sigm(o_) * tanh_fast(cn);

            // pack 2 f16 across the j-pair; agent write-through (at LLC)
            _Float16 hv = (_Float16)h_out;
            unsigned short hb16 = __builtin_bit_cast(unsigned short, hv);
            unsigned short pb = (unsigned short)__shfl_xor((int)hb16, 1, 64);
            if ((j & 1) == 0) {
                unsigned packed = (unsigned)hb16 | ((unsigned)pb << 16);
                __hip_atomic_store(
                    (unsigned*)(hbuf + (cur ^ 1) * (8 * HH) + m * HH + colg),
                    packed, __ATOMIC_RELAXED, __HIP_MEMORY_SCOPE_AGENT);
            }
        }

        // ---- arrive: __syncthreads drains every wave's vmcnt (h at LLC),
        //      then rank's flag is published ----
        __syncthreads();
        if constexpr (MODE != 2) {
            if (tid == 0)
                __hip_atomic_store(&gflags[rank], ep, __ATOMIC_RELAXED,
                                   __HIP_MEMORY_SCOPE_AGENT);
        }

        // ---- shadow work while group-mates arrive ----
        if (t + 1 < TT) {
            xacc = xgemm(t + 1);
            if (tid < 256) {
                bnmu  = pmean[(t + 1) * HH + colg];
                bniss = scale[(t + 1) * HH + colg] * rsqrtf(pvar[(t + 1) * HH + colg] + 1e-5f);
                bnoff = offs [(t + 1) * HH + colg];
            }
        }

        // ---- wait: direct poll of the group's 32 flags (no epoch hop) ----
        if constexpr (MODE == 2) {
            grid.sync();
        } else {
            if (tid < 64) {
                const int* fp = &gflags[tid & 31];
                for (;;) {
                    int v = __hip_atomic_load(fp, __ATOMIC_RELAXED,
                                              __HIP_MEMORY_SCOPE_AGENT);
                    if (__all(v >= ep)) break;
                    __builtin_amdgcn_s_sleep(1);
                }
            }
            __syncthreads();
        }
        ++ep;
        cur ^= 1;
    }

    // after the group's final barrier nobody reads hbuf; the fp32 result
    // lands inside this group's own 32 KiB chunk (== its hbuf region)
    if (tid < 256)
        out[(size_t)(g * 8 + m) * HH + colg] = h_out;
}

extern "C" void kernel_launch(void* const* d_in, const int* in_sizes, int n_in,
                              void* d_out, int out_size, void* d_ws, size_t ws_size,
                              hipStream_t stream) {
    const float* x     = (const float*)d_in[0];
    const float* w_xh  = (const float*)d_in[1];
    const float* w_hh  = (const float*)d_in[2];
    const float* bias  = (const float*)d_in[3];
    const float* scale = (const float*)d_in[4];
    const float* offs  = (const float*)d_in[5];
    const float* pmean = (const float*)d_in[6];
    const float* pvar  = (const float*)d_in[7];
    float* out = (float*)d_out;

    int* flags  = (int*)d_ws;                         // 2 KB: 8 groups x 64 slots
    _Float16* x16 = (_Float16*)((char*)d_ws + 4096);  // 32 MiB
    const size_t X16B = (size_t)BB * TT * FF * 2;
    const int mode = (ws_size >= X16B + 4096) ? 0 : (ws_size >= 4096 ? 1 : 2);

    if (mode <= 1) (void)hipMemsetAsync(d_ws, 0, 4096, stream);
    if (mode == 0) {
        const size_t nelem = (size_t)BB * TT * FF;
        cvt_x<<<dim3((unsigned)(nelem / (256 * 8))), 256, 0, stream>>>(x, x16);
    }

    void* args[] = {&x, &w_xh, &w_hh, &bias, &scale, &offs, &pmean, &pvar,
                    &x16, &flags, &out};
    const void* f = (mode == 0) ? (const void*)&lstm_rec<0>
                  : (mode == 1) ? (const void*)&lstm_rec<1>
                                : (const void*)&lstm_rec<2>;
    (void)hipLaunchCooperativeKernel(f, dim3(256), dim3(512), args, 0, stream);
}